// Round 2
// baseline (1119.067 us; speedup 1.0000x reference)
//
#include <hip/hip_runtime.h>
#include <hip/hip_bf16.h>
#include <math.h>

#define BB 16
#define NN 1024
#define CC 16
#define DD 64
#define TT 32

typedef __bf16 bf16;
typedef __bf16 bf16x8 __attribute__((ext_vector_type(8)));
typedef __bf16 bf16x4 __attribute__((ext_vector_type(4)));
typedef float f32x4 __attribute__((ext_vector_type(4)));

__device__ __forceinline__ void split2(float x, bf16& h, bf16& l) {
    h = (bf16)x;
    l = (bf16)(x - (float)h);
}

// ---------------- prep: A=bf16(Mvv+I) (exact), hi/lo state inits, hi/lo weight transposes ----------------
__global__ __launch_bounds__(256) void prep_kernel(
    const float* __restrict__ Mvv, const float* __restrict__ v_init,
    const float* __restrict__ W_v, const float* __restrict__ W_vv,
    bf16* __restrict__ Abf,
    bf16* __restrict__ vhHi, bf16* __restrict__ vhLo,
    bf16* __restrict__ vhTHi, bf16* __restrict__ vhTLo,
    bf16* __restrict__ WvTh, bf16* __restrict__ WvTl,
    bf16* __restrict__ WvvTh, bf16* __restrict__ WvvTl)
{
    int gid = blockIdx.x, tid = threadIdx.x;
    if (gid < 8192) {
        size_t idx = ((size_t)gid * 256 + tid) * 8;
        const float4* p = (const float4*)(Mvv + idx);
        float4 f0 = p[0], f1 = p[1];
        int j0 = (int)(idx & (NN - 1));
        int i  = (int)((idx >> 10) & (NN - 1));
        float v[8] = {f0.x, f0.y, f0.z, f0.w, f1.x, f1.y, f1.z, f1.w};
        int di = i - j0;
        if (di >= 0 && di < 8) v[di] += 1.0f;   // self loop; values {0,1,2} exact in bf16
        bf16x8 o;
        #pragma unroll
        for (int e = 0; e < 8; ++e) o[e] = (bf16)v[e];
        *(bf16x8*)(Abf + idx) = o;
    } else if (gid < 8704) {
        size_t idx = ((size_t)(gid - 8192) * 256 + tid) * 8;   // over B*N*D
        int d0 = (int)(idx & (DD - 1));
        bf16x8 oh, ol;
        #pragma unroll
        for (int e = 0; e < 8; ++e) { bf16 h, l; split2(v_init[d0 + e], h, l); oh[e] = h; ol[e] = l; }
        *(bf16x8*)(vhHi + idx) = oh;
        *(bf16x8*)(vhLo + idx) = ol;
    } else if (gid < 9216) {
        size_t idx = ((size_t)(gid - 8704) * 256 + tid) * 8;   // over B*D*N
        int d = (int)((idx >> 10) & (DD - 1));
        bf16 h, l; split2(v_init[d], h, l);
        bf16x8 oh, ol;
        #pragma unroll
        for (int e = 0; e < 8; ++e) { oh[e] = h; ol[e] = l; }
        *(bf16x8*)(vhTHi + idx) = oh;
        *(bf16x8*)(vhTLo + idx) = ol;
    } else {
        for (int e = tid; e < DD * DD; e += 256) {
            int n = e >> 6, k = e & 63;
            bf16 h, l;
            split2(W_v[k * DD + n], h, l);   // WvT[n][k] = W_v[k][n]
            WvTh[e] = h; WvTl[e] = l;
            split2(W_vv[k * DD + n], h, l);
            WvvTh[e] = h; WvvTl[e] = l;
        }
    }
}

// ---------------- per-step kernel: ch-update (redundant, fp32) + vh-update (split-bf16 MFMA) ----------------
__global__ __launch_bounds__(256) void step_kernel(
    const bf16* __restrict__ Abf,
    const bf16* __restrict__ vhHi_in, const bf16* __restrict__ vhLo_in,
    const bf16* __restrict__ vhTHi_in, const bf16* __restrict__ vhTLo_in,
    bf16* __restrict__ vhHi_out, bf16* __restrict__ vhLo_out,
    bf16* __restrict__ vhTHi_out, bf16* __restrict__ vhTLo_out,
    const float* __restrict__ ch_in, float* __restrict__ ch_out,
    const float* __restrict__ part_prev, float* __restrict__ part_out,
    const int* __restrict__ n_colors,
    const float* __restrict__ Wc, const float* __restrict__ Wcv, const float* __restrict__ bc,
    const float* __restrict__ Wvc, const float* __restrict__ bv,
    const bf16* __restrict__ WvTh, const bf16* __restrict__ WvTl,
    const bf16* __restrict__ WvvTh, const bf16* __restrict__ WvvTl,
    int t)
{
    __shared__ bf16 sA [64][136];   // A tile (+8 pad -> only 2-way conflicts, free)
    __shared__ bf16 sVh[64][136];   // vh^T hi tile [d][k]
    __shared__ bf16 sVl[64][136];   // vh^T lo tile [d][k]
    __shared__ bf16 sPh[64][72];    // v_agg hi exchange (row=m, col=d)
    __shared__ bf16 sPl[64][72];    // v_agg lo exchange
    __shared__ float s_tmp[64];
    __shared__ float s_mv[64];
    __shared__ float s_cvec[64];
    __shared__ float s_ch[CC][64];

    int tid  = threadIdx.x;
    int b    = blockIdx.x >> 4;
    int blkr = blockIdx.x & 15;
    int m0   = blkr * 64;
    int ncol = n_colors[b];

    // ---- phase 0: color-state update (every block redundantly; deterministic, fp32) ----
    if (t == 0) {
        if (tid < 64) {
            float cs = 0.f;
            for (int c = 0; c < ncol; ++c) cs += ch_in[(b * CC + c) * DD + tid];
            s_tmp[tid] = cs;
        }
        __syncthreads();
        if (tid < 64) {
            float cv = bv[tid];
            for (int k = 0; k < DD; ++k) cv += s_tmp[k] * Wvc[k * DD + tid];
            s_cvec[tid] = cv;
        }
    } else {
        if (tid < 64) {      // vsum over 64 partials of vh_t
            float vs = 0.f;
            const float* pp = part_prev + (size_t)b * 64 * DD + tid;
            for (int p = 0; p < 64; ++p) vs += pp[p * DD];
            s_tmp[tid] = vs;
        }
        __syncthreads();
        if (tid < 64) {      // mv[d'] = vsum @ W_cv
            float m = 0.f;
            for (int k = 0; k < DD; ++k) m += s_tmp[k] * Wcv[k * DD + tid];
            s_mv[tid] = m;
        }
        __syncthreads();
        {
            int dp = tid & 63, cg = tid >> 6;
            for (int ci = 0; ci < 4; ++ci) {
                int c = cg * 4 + ci;
                float s = bc[dp] + ((c < ncol) ? s_mv[dp] : 0.f);
                const float* chp = ch_in + (b * CC + c) * DD;
                for (int k = 0; k < DD; ++k) s += chp[k] * Wc[k * DD + dp];
                float cn = tanhf(s);
                s_ch[c][dp] = cn;
                ch_out[(b * CC + c) * DD + dp] = cn;   // identical across blocks of b
            }
        }
        __syncthreads();
        if (tid < 64) {
            float cs = 0.f;
            for (int c = 0; c < ncol; ++c) cs += s_ch[c][tid];
            s_tmp[tid] = cs;
        }
        __syncthreads();
        if (tid < 64) {
            float cv = bv[tid];
            for (int k = 0; k < DD; ++k) cv += s_tmp[k] * Wvc[k * DD + tid];
            s_cvec[tid] = cv;
        }
    }
    __syncthreads();

    // ---- phase 1: v_agg = (Mvv+I) @ (vh_hi + vh_lo) via MFMA (fp32-equivalent) ----
    int lane = tid & 63, w = tid >> 6;
    int l16 = lane & 15, lhi = lane >> 4;

    f32x4 acc[4];
    #pragma unroll
    for (int nt = 0; nt < 4; ++nt) acc[nt] = (f32x4){0.f, 0.f, 0.f, 0.f};

    const bf16* Arow = Abf + (size_t)b * NN * NN;
    const bf16* Vh   = vhTHi_in + (size_t)b * DD * NN;
    const bf16* Vl   = vhTLo_in + (size_t)b * DD * NN;

    for (int kt = 0; kt < NN; kt += 128) {
        #pragma unroll
        for (int i2 = 0; i2 < 4; ++i2) {
            int chunk = tid + 256 * i2;
            int r = chunk >> 4;
            int kc = (chunk & 15) * 8;
            *(uint4*)(&sA [r][kc]) = *(const uint4*)(Arow + (size_t)(m0 + r) * NN + kt + kc);
            *(uint4*)(&sVh[r][kc]) = *(const uint4*)(Vh + (size_t)r * NN + kt + kc);
            *(uint4*)(&sVl[r][kc]) = *(const uint4*)(Vl + (size_t)r * NN + kt + kc);
        }
        __syncthreads();
        #pragma unroll
        for (int kk = 0; kk < 4; ++kk) {
            bf16x8 a = *(const bf16x8*)(&sA[w * 16 + l16][kk * 32 + lhi * 8]);
            #pragma unroll
            for (int nt = 0; nt < 4; ++nt) {
                bf16x8 bh = *(const bf16x8*)(&sVh[nt * 16 + l16][kk * 32 + lhi * 8]);
                bf16x8 bl = *(const bf16x8*)(&sVl[nt * 16 + l16][kk * 32 + lhi * 8]);
                acc[nt] = __builtin_amdgcn_mfma_f32_16x16x32_bf16(a, bh, acc[nt], 0, 0, 0);
                acc[nt] = __builtin_amdgcn_mfma_f32_16x16x32_bf16(a, bl, acc[nt], 0, 0, 0);
            }
        }
        __syncthreads();
    }

    // ---- phase 2: pre = vh@W_v + v_agg@W_vv + cvec ; tanh ; split writes ----
    #pragma unroll
    for (int nt = 0; nt < 4; ++nt)
        #pragma unroll
        for (int r = 0; r < 4; ++r) {
            bf16 h, l; split2(acc[nt][r], h, l);
            sPh[w * 16 + lhi * 4 + r][nt * 16 + l16] = h;
            sPl[w * 16 + lhi * 4 + r][nt * 16 + l16] = l;
        }
    __syncthreads();

    f32x4 acc2[4];
    #pragma unroll
    for (int nt = 0; nt < 4; ++nt) {
        float cv = s_cvec[nt * 16 + l16];
        acc2[nt] = (f32x4){cv, cv, cv, cv};
    }

    const bf16* vrh = vhHi_in + (size_t)(b * NN + m0 + w * 16 + l16) * DD;
    const bf16* vrl = vhLo_in + (size_t)(b * NN + m0 + w * 16 + l16) * DD;
    #pragma unroll
    for (int kk = 0; kk < 2; ++kk) {
        bf16x8 a1h = *(const bf16x8*)(vrh + kk * 32 + lhi * 8);
        bf16x8 a1l = *(const bf16x8*)(vrl + kk * 32 + lhi * 8);
        bf16x8 a2h = *(const bf16x8*)(&sPh[w * 16 + l16][kk * 32 + lhi * 8]);
        bf16x8 a2l = *(const bf16x8*)(&sPl[w * 16 + l16][kk * 32 + lhi * 8]);
        #pragma unroll
        for (int nt = 0; nt < 4; ++nt) {
            int woff = (nt * 16 + l16) * DD + kk * 32 + lhi * 8;
            bf16x8 b1h = *(const bf16x8*)(WvTh + woff);
            bf16x8 b1l = *(const bf16x8*)(WvTl + woff);
            bf16x8 b2h = *(const bf16x8*)(WvvTh + woff);
            bf16x8 b2l = *(const bf16x8*)(WvvTl + woff);
            acc2[nt] = __builtin_amdgcn_mfma_f32_16x16x32_bf16(a1h, b1h, acc2[nt], 0, 0, 0);
            acc2[nt] = __builtin_amdgcn_mfma_f32_16x16x32_bf16(a1l, b1h, acc2[nt], 0, 0, 0);
            acc2[nt] = __builtin_amdgcn_mfma_f32_16x16x32_bf16(a1h, b1l, acc2[nt], 0, 0, 0);
            acc2[nt] = __builtin_amdgcn_mfma_f32_16x16x32_bf16(a2h, b2h, acc2[nt], 0, 0, 0);
            acc2[nt] = __builtin_amdgcn_mfma_f32_16x16x32_bf16(a2l, b2h, acc2[nt], 0, 0, 0);
            acc2[nt] = __builtin_amdgcn_mfma_f32_16x16x32_bf16(a2h, b2l, acc2[nt], 0, 0, 0);
        }
    }

    size_t vout_base = (size_t)b * NN * DD;
    #pragma unroll
    for (int nt = 0; nt < 4; ++nt) {
        float tv[4];
        #pragma unroll
        for (int r = 0; r < 4; ++r) tv[r] = tanhf(acc2[nt][r]);
        bf16x4 pkh, pkl;
        #pragma unroll
        for (int r = 0; r < 4; ++r) {
            bf16 h, l; split2(tv[r], h, l);
            int m = m0 + w * 16 + lhi * 4 + r;
            vhHi_out[vout_base + (size_t)m * DD + nt * 16 + l16] = h;
            vhLo_out[vout_base + (size_t)m * DD + nt * 16 + l16] = l;
            pkh[r] = h; pkl[r] = l;
        }
        *(bf16x4*)(vhTHi_out + (size_t)(b * DD + nt * 16 + l16) * NN + m0 + w * 16 + lhi * 4) = pkh;
        *(bf16x4*)(vhTLo_out + (size_t)(b * DD + nt * 16 + l16) * NN + m0 + w * 16 + lhi * 4) = pkl;

        float cs = tv[0] + tv[1] + tv[2] + tv[3];
        cs += __shfl_xor(cs, 16);
        cs += __shfl_xor(cs, 32);
        if (lhi == 0)
            part_out[((size_t)b * 64 + blkr * 4 + w) * DD + nt * 16 + l16] = cs;
    }
}

// ---------------- final: vote MLP + mean + sigmoid (fp32) ----------------
__global__ __launch_bounds__(256) void final_kernel(
    const bf16* __restrict__ vhHi, const bf16* __restrict__ vhLo,
    const float* __restrict__ W1, const float* __restrict__ b1,
    const float* __restrict__ W2, const float* __restrict__ b2, float* __restrict__ out)
{
    __shared__ float sW1[DD * 16];
    __shared__ float sW2[16];
    __shared__ float sb1[16];
    __shared__ float s_red[4];
    int b = blockIdx.x, tid = threadIdx.x;
    for (int e = tid; e < DD * 16; e += 256) sW1[e] = W1[e];
    if (tid < 16) { sW2[tid] = W2[tid]; sb1[tid] = b1[tid]; }
    __syncthreads();
    float bias2 = b2[0];
    float sum = 0.f;
    for (int i = 0; i < 4; ++i) {
        int n = tid + 256 * i;
        const bf16* rh = vhHi + (size_t)(b * NN + n) * DD;
        const bf16* rl = vhLo + (size_t)(b * NN + n) * DD;
        float h[16];
        #pragma unroll
        for (int j = 0; j < 16; ++j) h[j] = sb1[j];
        #pragma unroll
        for (int q = 0; q < 8; ++q) {
            bf16x8 v8 = *(const bf16x8*)(rh + q * 8);
            bf16x8 l8 = *(const bf16x8*)(rl + q * 8);
            #pragma unroll
            for (int e = 0; e < 8; ++e) {
                float xv = (float)v8[e] + (float)l8[e];
                #pragma unroll
                for (int j = 0; j < 16; ++j) h[j] += xv * sW1[(q * 8 + e) * 16 + j];
            }
        }
        float vote = bias2;
        #pragma unroll
        for (int j = 0; j < 16; ++j) vote += sW2[j] * (1.f / (1.f + expf(-h[j])));
        sum += vote;
    }
    #pragma unroll
    for (int off = 1; off < 64; off <<= 1) sum += __shfl_xor(sum, off);
    if ((tid & 63) == 0) s_red[tid >> 6] = sum;
    __syncthreads();
    if (tid == 0) {
        float tot = s_red[0] + s_red[1] + s_red[2] + s_red[3];
        float mean = tot / (float)NN;
        out[b] = 1.f / (1.f + expf(-mean));
    }
}

extern "C" void kernel_launch(void* const* d_in, const int* in_sizes, int n_in,
                              void* d_out, int out_size, void* d_ws, size_t ws_size,
                              hipStream_t stream) {
    const float* Mvv  = (const float*)d_in[0];
    const int*   ncol = (const int*)d_in[1];
    const float* vini = (const float*)d_in[2];
    const float* ch0  = (const float*)d_in[3];
    const float* W_v  = (const float*)d_in[4];
    const float* W_vv = (const float*)d_in[5];
    const float* W_vc = (const float*)d_in[6];
    const float* b_v  = (const float*)d_in[7];
    const float* W_c  = (const float*)d_in[8];
    const float* W_cv = (const float*)d_in[9];
    const float* b_c  = (const float*)d_in[10];
    const float* W1   = (const float*)d_in[11];
    const float* b1   = (const float*)d_in[12];
    const float* W2   = (const float*)d_in[13];
    const float* b2   = (const float*)d_in[14];

    char* base = (char*)d_ws;
    size_t off = 0;
    bf16* Abf = (bf16*)(base + off); off += (size_t)BB * NN * NN * 2;       // 33,554,432
    const size_t SVH = (size_t)BB * NN * DD * 2;                             // 2,097,152
    bf16* vhHi[2]  = {(bf16*)(base + off), (bf16*)(base + off + SVH)}; off += 2 * SVH;
    bf16* vhLo[2]  = {(bf16*)(base + off), (bf16*)(base + off + SVH)}; off += 2 * SVH;
    bf16* vhTHi[2] = {(bf16*)(base + off), (bf16*)(base + off + SVH)}; off += 2 * SVH;
    bf16* vhTLo[2] = {(bf16*)(base + off), (bf16*)(base + off + SVH)}; off += 2 * SVH;
    const size_t SCH = (size_t)BB * CC * DD * 4;                             // 65,536
    float* chb[2] = {(float*)(base + off), (float*)(base + off + SCH)}; off += 2 * SCH;
    const size_t SPB = (size_t)BB * 64 * DD * 4;                             // 262,144
    float* pb[2] = {(float*)(base + off), (float*)(base + off + SPB)}; off += 2 * SPB;
    bf16* WvTh  = (bf16*)(base + off); off += DD * DD * 2;
    bf16* WvTl  = (bf16*)(base + off); off += DD * DD * 2;
    bf16* WvvTh = (bf16*)(base + off); off += DD * DD * 2;
    bf16* WvvTl = (bf16*)(base + off); off += DD * DD * 2;

    prep_kernel<<<9217, 256, 0, stream>>>(Mvv, vini, W_v, W_vv, Abf,
        vhHi[0], vhLo[0], vhTHi[0], vhTLo[0], WvTh, WvTl, WvvTh, WvvTl);

    for (int t = 0; t < TT; ++t) {
        const float* ch_in = (t <= 1) ? ch0 : chb[(t - 1) & 1];
        int i = t & 1, o = (t + 1) & 1;
        step_kernel<<<256, 256, 0, stream>>>(Abf,
            vhHi[i], vhLo[i], vhTHi[i], vhTLo[i],
            vhHi[o], vhLo[o], vhTHi[o], vhTLo[o],
            ch_in, chb[t & 1],
            pb[(t + 1) & 1], pb[t & 1],
            ncol, W_c, W_cv, b_c, W_vc, b_v,
            WvTh, WvTl, WvvTh, WvvTl, t);
    }

    final_kernel<<<16, 256, 0, stream>>>(vhHi[0], vhLo[0], W1, b1, W2, b2, (float*)d_out);
}